// Round 5
// baseline (448.968 us; speedup 1.0000x reference)
//
#include <hip/hip_runtime.h>
#include <hip/hip_bf16.h>

#define N_NODES   50000
#define N_PAD     50048                 // ceil64
#define N_EDGES   800000
#define N_REL     16
#define N_GRAPHS  64
#define DIM       128
#define FC_DIM    256
#define N_CLASSES 16

#define NCOARSE   782                   // dst>>6 bins
#define NCH       196                   // edge chunks
#define CHSZ      4096
#define POOL_CH   64

#define NBLK_CX   27200                 // XW_TOTAL/256
#define XW_TOTAL  (N_PAD * DIM + 2 * 17 * 16384)

// ---- ws layout (bytes, 256-aligned) ----
#define WS_HG     0                     // 32768 } memset
#define WS_CNT    32768                 // 256   } region
#define MEMSET_SZ 33024
#define WS_BLKH   33024                 // 196*782*4 = 613088 -> 613376
#define WS_COFS   646400                // 3328 (783 ints)
#define WS_RTMP   649728                // 3200000
#define WS_RECS   3849728               // 3200000
#define WS_OFFSDR 7049728               // (782*1024+1)*4 -> 3203328
#define WS_X1     10253056              // 12812288
#define WS_X2     23065344              // 12812288
#define WS_AGG    35877632              // 12812288
#define WS_WB     48689920              // 1114112  (bf16 W, 2 layers x 17 x 128x128)

typedef __attribute__((ext_vector_type(8))) short bf16x8;
typedef __attribute__((ext_vector_type(4))) float f32x4;

__device__ __forceinline__ void atomAddF(float* p, float v) {
#if defined(__gfx90a__) || defined(__gfx942__) || defined(__gfx950__)
    unsafeAtomicAdd(p, v);
#else
    atomicAdd(p, v);
#endif
}

__device__ __forceinline__ float bf2f(unsigned int u) {
    union { float f; unsigned int i; } x; x.i = u << 16; return x.f;
}
__device__ __forceinline__ unsigned short f2bf(float f) {
    union { float f; unsigned int u; } x; x.f = f;
    unsigned int r = x.u + 0x7fff + ((x.u >> 16) & 1);
    return (unsigned short)(r >> 16);
}
__device__ __forceinline__ void accum8(float* qa, uint4 u) {
    qa[0] += bf2f(u.x & 0xffff); qa[1] += bf2f(u.x >> 16);
    qa[2] += bf2f(u.y & 0xffff); qa[3] += bf2f(u.y >> 16);
    qa[4] += bf2f(u.z & 0xffff); qa[5] += bf2f(u.z >> 16);
    qa[6] += bf2f(u.w & 0xffff); qa[7] += bf2f(u.w >> 16);
}
__device__ __forceinline__ void pack16(const float* qa, unsigned short* dst) {
    #pragma unroll
    for (int j = 0; j < 2; ++j) {
        uint4 w;
        w.x = ((unsigned int)f2bf(qa[j*8+1]) << 16) | f2bf(qa[j*8+0]);
        w.y = ((unsigned int)f2bf(qa[j*8+3]) << 16) | f2bf(qa[j*8+2]);
        w.z = ((unsigned int)f2bf(qa[j*8+5]) << 16) | f2bf(qa[j*8+4]);
        w.w = ((unsigned int)f2bf(qa[j*8+7]) << 16) | f2bf(qa[j*8+6]);
        ((uint4*)dst)[j] = w;
    }
}

// ---- fused: per-chunk coarse dst histogram (blocks 0..195) + convX/convW ----
__global__ __launch_bounds__(256) void k_h1cx(
    const int* __restrict__ dst,
    int* __restrict__ blockHist,
    const float* __restrict__ h, unsigned short* __restrict__ x1,
    const float* __restrict__ W1, const float* __restrict__ Ws1,
    const float* __restrict__ W2, const float* __restrict__ Ws2,
    unsigned short* __restrict__ Wb)
{
    __shared__ int hl[NCOARSE];
    int t = threadIdx.x;
    if (blockIdx.x < NCH) {
        int b = blockIdx.x;
        for (int i = t; i < NCOARSE; i += 256) hl[i] = 0;
        __syncthreads();
        int e0 = b * CHSZ;
        int eend = min(e0 + CHSZ, N_EDGES);
        for (int e = e0 + t; e < eend; e += 256)
            atomicAdd(&hl[dst[e] >> 6], 1);              // LDS atomic
        __syncthreads();
        for (int i = t; i < NCOARSE; i += 256) blockHist[b * NCOARSE + i] = hl[i];
    } else {
        int id = (blockIdx.x - NCH) * 256 + t;
        if (id < N_PAD * DIM) {
            int v = id >> 7;
            x1[id] = (v < N_NODES) ? f2bf(h[id]) : (unsigned short)0;
        } else {
            int tt = id - N_PAD * DIM;
            int l = tt / 278528, rem = tt % 278528;
            int r = rem >> 14, rr = rem & 16383;
            int n = rr >> 7, k = rr & 127;
            const float* W  = l ? W2 : W1;
            const float* Ws = l ? Ws2 : Ws1;
            float v = (r < 16) ? W[r * 16384 + k * 128 + n] : Ws[k * 128 + n];
            Wb[tt] = f2bf(v);
        }
    }
}

// ---- per-bin scan across chunks (parallel, 782 blocks) ----
__global__ __launch_bounds__(256) void k_csA(int* __restrict__ blockHist,
                                             int* __restrict__ cOffs)
{
    __shared__ int sc[2][256];
    int i = blockIdx.x, t = threadIdx.x;
    int v = (t < NCH) ? blockHist[t * NCOARSE + i] : 0;
    sc[0][t] = v; __syncthreads();
    int cur = 0;
    for (int o = 1; o < 256; o <<= 1) {
        sc[cur ^ 1][t] = sc[cur][t] + ((t >= o) ? sc[cur][t - o] : 0);
        __syncthreads();
        cur ^= 1;
    }
    if (t < NCH) blockHist[t * NCOARSE + i] = sc[cur][t] - v;   // exclusive, no base
    if (t == NCH - 1) cOffs[i] = sc[cur][t];                    // bin total
}

// ---- bin-base scan (1 block) ----
__global__ __launch_bounds__(1024) void k_csB(int* __restrict__ cOffs)
{
    __shared__ int c1[1024], c2[1024];
    int t = threadIdx.x;
    int v = (t < NCOARSE) ? cOffs[t] : 0;
    c1[t] = v; __syncthreads();
    int* cur = c1; int* nxt = c2;
    for (int o = 1; o < 1024; o <<= 1) {
        nxt[t] = cur[t] + ((t >= o) ? cur[t - o] : 0);
        __syncthreads();
        int* tmp = cur; cur = nxt; nxt = tmp;
    }
    if (t < NCOARSE) cOffs[t] = cur[t] - v;
    if (t == NCOARSE) cOffs[NCOARSE] = cur[NCOARSE - 1];
}

// ---- scatter to coarse segments: record = src<<10 | dstlow6<<4 | rel ----
__global__ __launch_bounds__(256) void k_scat1(
    const int* __restrict__ src, const int* __restrict__ dst, const int* __restrict__ rel,
    const int* __restrict__ blockHist, const int* __restrict__ cOffs,
    unsigned int* __restrict__ rtmp)
{
    __shared__ int baseL[NCOARSE];
    __shared__ int hl[NCOARSE];
    int b = blockIdx.x, t = threadIdx.x;
    for (int i = t; i < NCOARSE; i += 256) {
        baseL[i] = blockHist[b * NCOARSE + i] + cOffs[i];
        hl[i] = 0;
    }
    __syncthreads();
    int e0 = b * CHSZ;
    int eend = min(e0 + CHSZ, N_EDGES);
    for (int e = e0 + t; e < eend; e += 256) {
        int d = dst[e];
        int c = d >> 6;
        int rank = atomicAdd(&hl[c], 1);                 // LDS atomic
        rtmp[baseL[c] + rank] = ((unsigned int)src[e] << 10)
                              | ((unsigned int)(d & 63) << 4)
                              | (unsigned int)rel[e];
    }
}

// ---- per coarse bin: 1024-way ((dst&63)<<4|rel) counting sort -> recs(src) + CSR ----
__global__ __launch_bounds__(256) void k_p2(
    const unsigned int* __restrict__ rtmp, const int* __restrict__ cOffs,
    unsigned int* __restrict__ recs, int* __restrict__ offsDR)
{
    __shared__ int cnt[1024];
    __shared__ int part[256], part2[256];
    int i = blockIdx.x, t = threadIdx.x;
    int segB = cOffs[i], segE = cOffs[i + 1];
    for (int k = t; k < 1024; k += 256) cnt[k] = 0;
    __syncthreads();
    for (int e = segB + t; e < segE; e += 256)
        atomicAdd(&cnt[rtmp[e] & 1023u], 1);
    __syncthreads();
    int b4 = t * 4;
    int s0 = cnt[b4], s1 = cnt[b4+1], s2 = cnt[b4+2], s3 = cnt[b4+3];
    int tsum = s0 + s1 + s2 + s3;
    part[t] = tsum;
    __syncthreads();
    int* cur = part; int* nxt = part2;
    for (int o = 1; o < 256; o <<= 1) {
        nxt[t] = cur[t] + ((t >= o) ? cur[t - o] : 0);
        __syncthreads();
        int* tmp = cur; cur = nxt; nxt = tmp;
    }
    int excl = cur[t] - tsum + segB;
    cnt[b4]     = excl;
    cnt[b4 + 1] = excl + s0;
    cnt[b4 + 2] = excl + s0 + s1;
    cnt[b4 + 3] = excl + s0 + s1 + s2;
    __syncthreads();
    for (int k = t; k < 1024; k += 256) offsDR[i * 1024 + k] = cnt[k];
    if (i == NCOARSE - 1 && t == 0) offsDR[NCOARSE * 1024] = segE;
    for (int e = segB + t; e < segE; e += 256) {
        unsigned int r = rtmp[e];
        int pos = atomicAdd(&cnt[r & 1023u], 1);
        recs[pos] = r >> 10;
    }
}

// ---- fused RGCN layer: per 64-dst bin, per rel: sum x[src] rows (f32) ->
// bf16 S tile -> MFMA x W[r], accumulating across all 17 rels (16 + self)
// in registers. No T materialization; gathers hit L2/L3-resident x. ----
__global__ __launch_bounds__(256) void k_rgcn(
    const unsigned short* __restrict__ x, const unsigned short* __restrict__ Wb,
    const unsigned int* __restrict__ recs, const int* __restrict__ offsDR,
    const float* __restrict__ bias, unsigned short* __restrict__ out, int relu)
{
    __shared__ __attribute__((aligned(16))) unsigned short S[64 * 136];
    __shared__ int sOffs[1025];
    int tid = threadIdx.x;
    int bin = blockIdx.x;                    // one coarse bin = 64 dsts
    int v0 = bin * 64;
    for (int k = tid; k < 1025; k += 256) sOffs[k] = offsDR[bin * 1024 + k];

    int w = tid >> 6, l = tid & 63, nl = l & 15, q = l >> 4;
    int gh = tid >> 3, s = tid & 7;          // build role: 8 threads/dst

    f32x4 acc[4][2];
    #pragma unroll
    for (int m = 0; m < 4; ++m) {
        acc[m][0] = (f32x4){0.f, 0.f, 0.f, 0.f};
        acc[m][1] = (f32x4){0.f, 0.f, 0.f, 0.f};
    }
    __syncthreads();

    for (int r = 0; r < 17; ++r) {
        // build S rows (two halves of 32 dsts; 8 threads x 16 dims each)
        #pragma unroll
        for (int hf = 0; hf < 2; ++hf) {
            int g = hf * 32 + gh;
            float qa[16];
            #pragma unroll
            for (int j = 0; j < 16; ++j) qa[j] = 0.f;
            if (r == 16) {
                const uint4* xp = (const uint4*)(x + (size_t)(v0 + g) * DIM + s * 16);
                uint4 u0 = xp[0], u1 = xp[1];
                accum8(qa, u0); accum8(qa + 8, u1);
            } else {
                int o0 = sOffs[g * 16 + r], o1 = sOffs[g * 16 + r + 1];
                for (int e = o0; e < o1; ++e) {
                    const uint4* xp = (const uint4*)(x + (size_t)recs[e] * DIM + s * 16);
                    uint4 u0 = xp[0], u1 = xp[1];
                    accum8(qa, u0); accum8(qa + 8, u1);
                }
            }
            pack16(qa, &S[g * 136 + s * 16]);
        }
        __syncthreads();
        // MFMA: 64 rows x 128 cols, phaseA-verified fragment layout
        const unsigned short* wr = Wb + r * 16384;
        #pragma unroll
        for (int kc = 0; kc < 4; ++kc) {
            bf16x8 b0 = *(const bf16x8*)(wr + (w * 32 + nl) * 128 + kc * 32 + q * 8);
            bf16x8 b1 = *(const bf16x8*)(wr + (w * 32 + 16 + nl) * 128 + kc * 32 + q * 8);
            #pragma unroll
            for (int m = 0; m < 4; ++m) {
                bf16x8 a = *(const bf16x8*)(&S[(m * 16 + nl) * 136 + kc * 32 + q * 8]);
                acc[m][0] = __builtin_amdgcn_mfma_f32_16x16x32_bf16(a, b0, acc[m][0], 0, 0, 0);
                acc[m][1] = __builtin_amdgcn_mfma_f32_16x16x32_bf16(a, b1, acc[m][1], 0, 0, 0);
            }
        }
        __syncthreads();                     // S reads done before next rel
    }

    // epilogue: bias + relu -> S staging -> coalesced store
    float bv0 = bias[w * 32 + nl], bv1 = bias[w * 32 + 16 + nl];
    #pragma unroll
    for (int m = 0; m < 4; ++m) {
        #pragma unroll
        for (int reg = 0; reg < 4; ++reg) {
            int row = m * 16 + q * 4 + reg;
            float f0 = acc[m][0][reg] + bv0;
            float f1 = acc[m][1][reg] + bv1;
            if (relu) { f0 = fmaxf(f0, 0.f); f1 = fmaxf(f1, 0.f); }
            S[row * 136 + (w * 32 + nl)]      = f2bf(f0);
            S[row * 136 + (w * 32 + 16 + nl)] = f2bf(f1);
        }
    }
    __syncthreads();
    {
        unsigned short* Ob = out + (size_t)v0 * DIM;
        #pragma unroll
        for (int it = 0; it < 4; ++it) {
            int c = tid + it * 256;
            int rw = c >> 4, k8 = c & 15;
            uint4 vv = *(const uint4*)(&S[rw * 136 + k8 * 8]);
            *(uint4*)(Ob + rw * DIM + k8 * 8) = vv;
        }
    }
}

__global__ void k_pool(const unsigned short* __restrict__ agg2, const int* __restrict__ gids,
                       float* __restrict__ hg_sum, int* __restrict__ cnt)
{
    int d  = threadIdx.x;
    int n0 = blockIdx.x * POOL_CH;
    int nend = min(n0 + POOL_CH, N_NODES);
    if (n0 >= N_NODES) return;
    int curg = gids[n0];
    float run = 0.f;
    for (int n = n0; n < nend; ++n) {
        int g = gids[n];
        if (g != curg) { atomAddF(&hg_sum[curg*DIM + d], run); run = 0.f; curg = g; }
        run += fmaxf(bf2f((unsigned int)agg2[n*DIM + d]), 0.f);
    }
    atomAddF(&hg_sum[curg*DIM + d], run);
    if (d == 0) {
        int cg = gids[n0]; int rl = 0;
        for (int n = n0; n < nend; ++n) {
            int g = gids[n];
            if (g != cg) { atomicAdd(&cnt[cg], rl); rl = 0; cg = g; }
            rl++;
        }
        atomicAdd(&cnt[cg], rl);
    }
}

__global__ __launch_bounds__(256) void k_head(
    const float* __restrict__ hg_sum, const int* __restrict__ cnt,
    const float* __restrict__ Wfc, const float* __restrict__ bfc,
    const float* __restrict__ Wc, const float* __restrict__ bc,
    float* __restrict__ out)
{
    int g = blockIdx.x, t = threadIdx.x;
    __shared__ float hgl[DIM];
    __shared__ float fcl[FC_DIM];
    __shared__ float lg[N_CLASSES];
    if (t < DIM) {
        float c = (float)max(cnt[g], 1);
        hgl[t] = hg_sum[g*DIM + t] / c;
    }
    __syncthreads();
    {
        float sv = bfc[t];
        #pragma unroll 4
        for (int k = 0; k < DIM; ++k) sv += hgl[k] * Wfc[k*FC_DIM + t];
        fcl[t] = fmaxf(sv, 0.f);
    }
    __syncthreads();
    if (t < N_CLASSES) {
        float lgt = bc[t];
        #pragma unroll 4
        for (int k = 0; k < FC_DIM; ++k) lgt += fcl[k] * Wc[k*N_CLASSES + t];
        lg[t] = lgt;
    }
    __syncthreads();
    if (t < N_CLASSES) {
        float m = lg[0];
        #pragma unroll
        for (int c = 1; c < N_CLASSES; ++c) m = fmaxf(m, lg[c]);
        float sden = 0.f;
        #pragma unroll
        for (int c = 0; c < N_CLASSES; ++c) sden += expf(lg[c] - m);
        out[g*N_CLASSES + t] = expf(lg[t] - m) / sden;
    }
}

extern "C" void kernel_launch(void* const* d_in, const int* in_sizes, int n_in,
                              void* d_out, int out_size, void* d_ws, size_t ws_size,
                              hipStream_t stream)
{
    const float* h   = (const float*)d_in[0];
    const int*   src = (const int*)d_in[1];
    const int*   dst = (const int*)d_in[2];
    const int*   rel = (const int*)d_in[3];
    const int*   gid = (const int*)d_in[4];
    const float* W1  = (const float*)d_in[5];
    const float* Ws1 = (const float*)d_in[6];
    const float* b1  = (const float*)d_in[7];
    const float* W2  = (const float*)d_in[8];
    const float* Ws2 = (const float*)d_in[9];
    const float* b2  = (const float*)d_in[10];
    const float* Wfc = (const float*)d_in[11];
    const float* bfc = (const float*)d_in[12];
    const float* Wc  = (const float*)d_in[13];
    const float* bc  = (const float*)d_in[14];
    float* out = (float*)d_out;

    char* ws = (char*)d_ws;
    float* hgsum = (float*)(ws + WS_HG);
    int*   cnt   = (int*)(ws + WS_CNT);
    int*   blkH  = (int*)(ws + WS_BLKH);
    int*   cOffs = (int*)(ws + WS_COFS);
    unsigned int* rtmp = (unsigned int*)(ws + WS_RTMP);
    unsigned int* recs = (unsigned int*)(ws + WS_RECS);
    int*   offsDR = (int*)(ws + WS_OFFSDR);
    unsigned short* x1  = (unsigned short*)(ws + WS_X1);
    unsigned short* x2  = (unsigned short*)(ws + WS_X2);
    unsigned short* agg = (unsigned short*)(ws + WS_AGG);
    unsigned short* Wb  = (unsigned short*)(ws + WS_WB);

    hipMemsetAsync(ws + WS_HG, 0, MEMSET_SZ, stream);   // hg + cnt

    k_h1cx<<<NCH + NBLK_CX, 256, 0, stream>>>(dst, blkH, h, x1, W1, Ws1, W2, Ws2, Wb);
    k_csA<<<NCOARSE, 256, 0, stream>>>(blkH, cOffs);
    k_csB<<<1, 1024, 0, stream>>>(cOffs);
    k_scat1<<<NCH, 256, 0, stream>>>(src, dst, rel, blkH, cOffs, rtmp);
    k_p2<<<NCOARSE, 256, 0, stream>>>(rtmp, cOffs, recs, offsDR);

    k_rgcn<<<NCOARSE, 256, 0, stream>>>(x1, Wb, recs, offsDR, b1, x2, 1);
    k_rgcn<<<NCOARSE, 256, 0, stream>>>(x2, Wb + 17 * 16384, recs, offsDR, b2, agg, 0);

    k_pool<<<(N_PAD + POOL_CH - 1) / POOL_CH, 128, 0, stream>>>(agg, gid, hgsum, cnt);
    k_head<<<N_GRAPHS, 256, 0, stream>>>(hgsum, cnt, Wfc, bfc, Wc, bc, out);
}